// Round 8
// baseline (499.239 us; speedup 1.0000x reference)
//
#include <hip/hip_runtime.h>
#include <hip/hip_bf16.h>

// GCN, CSR-gather, pre-transformed tables, locality-staged CSR build:
//   bin_edges: LDS counting-sort edges into 196 dst-buckets (packed u32)
//   bucket_deg / csr_fill_b: per-bucket LDS histogram / cursors -> localized writes
//   T = f(X)*dinv ; y[d] = dinv[d]*(sum T[s] + T[d])@W + b

#define CHUNK 8192

// ---- bin edges by dst>>8, LDS chunk-sort, coalesced flush ----
__global__ __launch_bounds__(256) void bin_edges(
        const int* __restrict__ src, const int* __restrict__ dst,
        int* __restrict__ gcur, unsigned* __restrict__ binned,
        int E, int nbuck, int cap) {
    __shared__ unsigned sorted[CHUNK];
    __shared__ int hist[256], base[256], pos[256];
    int t = threadIdx.x;
    for (int chunk = blockIdx.x * CHUNK; chunk < E; chunk += gridDim.x * CHUNK) {
        int cend = min(chunk + CHUNK, E);
        hist[t] = 0;
        __syncthreads();
        for (int i = chunk + t; i < cend; i += 256)
            atomicAdd(&hist[dst[i] >> 8], 1);
        __syncthreads();
        int v = hist[t];
        base[t] = v;
        __syncthreads();
        for (int o = 1; o < 256; o <<= 1) {
            int u = (t >= o) ? base[t - o] : 0;
            __syncthreads();
            base[t] += u;
            __syncthreads();
        }
        int excl = base[t] - v;
        __syncthreads();
        base[t] = excl;
        pos[t] = excl;
        __syncthreads();
        for (int i = chunk + t; i < cend; i += 256) {
            int d = dst[i];
            int b = d >> 8;
            int p = atomicAdd(&pos[b], 1);
            sorted[p] = ((unsigned)(d & 255) << 24) | (unsigned)src[i];
        }
        __syncthreads();
        int wid = t >> 6, lane = t & 63;
        for (int b = wid; b < nbuck; b += 4) {
            int lo = base[b], hi = pos[b];
            int cnt = hi - lo;
            if (cnt == 0) continue;
            int g;
            if (lane == 0) g = atomicAdd(&gcur[b], cnt);
            g = __shfl(g, 0, 64);
            unsigned* out = binned + (size_t)b * cap + g;
            for (int k = lane; k < cnt; k += 64) out[k] = sorted[lo + k];
        }
        __syncthreads();
    }
}

// ---- per-bucket degree histogram ----
__global__ __launch_bounds__(256) void bucket_deg(
        const unsigned* __restrict__ binned, const int* __restrict__ gcur,
        int* __restrict__ degi, int nbuck, int cap, int n) {
    __shared__ int h[256];
    for (int b = blockIdx.x; b < nbuck; b += gridDim.x) {
        h[threadIdx.x] = 0;
        __syncthreads();
        int cnt = gcur[b];
        const unsigned* p = binned + (size_t)b * cap;
        for (int i = threadIdx.x; i < cnt; i += 256)
            atomicAdd(&h[p[i] >> 24], 1);
        __syncthreads();
        int node = b * 256 + threadIdx.x;
        if (node < n) degi[node] = h[threadIdx.x];
        __syncthreads();
    }
}

__global__ void scan_part(const int* __restrict__ degi, int* __restrict__ part, int n) {
    __shared__ int ls[256];
    int i = blockIdx.x * 256 + threadIdx.x;
    ls[threadIdx.x] = (i < n) ? degi[i] : 0;
    __syncthreads();
    for (int o = 128; o > 0; o >>= 1) {
        if (threadIdx.x < o) ls[threadIdx.x] += ls[threadIdx.x + o];
        __syncthreads();
    }
    if (threadIdx.x == 0) part[blockIdx.x] = ls[0];
}

__global__ void scan_root(int* __restrict__ part, int nblk) {   // nblk <= 256
    __shared__ int ls[256];
    int t = threadIdx.x;
    int v = (t < nblk) ? part[t] : 0;
    ls[t] = v;
    __syncthreads();
    for (int o = 1; o < 256; o <<= 1) {
        int u = (t >= o) ? ls[t - o] : 0;
        __syncthreads();
        ls[t] += u;
        __syncthreads();
    }
    if (t < nblk) part[t] = ls[t] - v;   // exclusive
}

__global__ void scan_write(const int* __restrict__ degi, const int* __restrict__ part,
                           int* __restrict__ off, float* __restrict__ dinv, int n) {
    __shared__ int ls[256];
    int t = threadIdx.x, i = blockIdx.x * 256 + t;
    int d = (i < n) ? degi[i] : 0;
    ls[t] = d;
    __syncthreads();
    for (int o = 1; o < 256; o <<= 1) {
        int u = (t >= o) ? ls[t - o] : 0;
        __syncthreads();
        ls[t] += u;
        __syncthreads();
    }
    if (i < n) {
        int o0 = part[blockIdx.x] + ls[t] - d;
        off[i] = o0;
        dinv[i] = rsqrtf((float)d + 1.0f);   // +1 self loop
        if (i == n - 1) off[n] = o0 + d;
    }
}

// ---- per-bucket CSR fill: LDS cursors, writes localized to ~32KB region ----
__global__ __launch_bounds__(256) void csr_fill_b(
        const unsigned* __restrict__ binned, const int* __restrict__ gcur,
        const int* __restrict__ off, int* __restrict__ csr,
        int nbuck, int cap, int n) {
    __shared__ int lcur[256];
    for (int b = blockIdx.x; b < nbuck; b += gridDim.x) {
        int node = b * 256 + threadIdx.x;
        lcur[threadIdx.x] = (node < n) ? off[node] : 0;
        __syncthreads();
        int cnt = gcur[b];
        const unsigned* p = binned + (size_t)b * cap;
        for (int i = threadIdx.x; i < cnt; i += 256) {
            unsigned e = p[i];
            int pos = atomicAdd(&lcur[e >> 24], 1);
            csr[pos] = (int)(e & 0xFFFFFFu);
        }
        __syncthreads();
    }
}

// ---- T1 = x * dinv ----
__global__ void prescale(const float* __restrict__ x, const float* __restrict__ dinv,
                         float* __restrict__ T, int n) {
    int tid = blockIdx.x * blockDim.x + threadIdx.x;
    int stride = gridDim.x * blockDim.x;
    int total = n * 16;            // float4 count
    const float4* x4 = (const float4*)x;
    float4* T4 = (float4*)T;
    for (int i = tid; i < total; i += stride) {
        float4 v = x4[i];
        float dv = dinv[i >> 4];
        v.x *= dv; v.y *= dv; v.z *= dv; v.w *= dv;
        T4[i] = v;
    }
}

// ---- T2 = relu(BN(y)) * dinv ----
__global__ void bnrelu_scale(const float* __restrict__ Y, const double* __restrict__ stats,
                             const float* __restrict__ g, const float* __restrict__ bt,
                             const float* __restrict__ dinv, float* __restrict__ T, int n) {
    int f = threadIdx.x & 63;
    double mean = stats[f] / n;
    double var  = stats[64 + f] / n - mean * mean;
    float scale = (float)(1.0 / sqrt(var + 1e-5)) * g[f];
    float shift = bt[f] - (float)mean * scale;
    int tid = blockIdx.x * blockDim.x + threadIdx.x;
    int stride = gridDim.x * blockDim.x;   // multiple of 64
    for (int i = tid; i < n * 64; i += stride) {
        float v = fmaxf(Y[i] * scale + shift, 0.f);
        T[i] = v * dinv[i >> 6];
    }
}

// ---- fused layer: pure gather-sum -> @W -> *dinv + b -> stats ----
__global__ __launch_bounds__(256) void agg_mm(
        const float4* __restrict__ T4, const int* __restrict__ csr,
        const int* __restrict__ off, const float* __restrict__ dinv,
        const float* __restrict__ W, const float* __restrict__ bias,
        double* __restrict__ stats_out, float* __restrict__ Y, int n) {
    __shared__ float Wl[64 * 64];
    __shared__ double ls[256], lq[256];
    for (int t = threadIdx.x; t < 64 * 64; t += blockDim.x) Wl[t] = W[t];

    int lane = threadIdx.x & 63;
    int slot = lane >> 3;      // 8 edge slots
    int fl   = lane & 7;       // floats 8*fl .. 8*fl+7 (two float4)
    float bv = bias[lane];
    __syncthreads();

    int wave  = (blockIdx.x * blockDim.x + threadIdx.x) >> 6;
    int nwave = (gridDim.x * blockDim.x) >> 6;
    double s = 0.0, sq = 0.0;

    for (int i0 = wave; i0 < n; i0 += 2 * nwave) {
        int i1 = i0 + nwave;
        bool has1 = (i1 < n);
        int b0 = off[i0], e0 = off[i0 + 1];
        int b1 = 0, e1 = 0;
        if (has1) { b1 = off[i1]; e1 = off[i1 + 1]; }

        float4 a0l = {0,0,0,0}, a0h = {0,0,0,0};
        float4 a1l = {0,0,0,0}, a1h = {0,0,0,0};
        if (slot == 0) {                       // self term in slot 0 only
            a0l = T4[(size_t)i0 * 16 + fl * 2];
            a0h = T4[(size_t)i0 * 16 + fl * 2 + 1];
            if (has1) {
                a1l = T4[(size_t)i1 * 16 + fl * 2];
                a1h = T4[(size_t)i1 * 16 + fl * 2 + 1];
            }
        }

        int c0 = b0 + slot, c1 = b1 + slot;
        while (c0 < e0 || (has1 && c1 < e1)) {
            if (c0 < e0) {
                int sr = csr[c0];
                float4 vl = T4[(size_t)sr * 16 + fl * 2];
                float4 vh = T4[(size_t)sr * 16 + fl * 2 + 1];
                a0l.x += vl.x; a0l.y += vl.y; a0l.z += vl.z; a0l.w += vl.w;
                a0h.x += vh.x; a0h.y += vh.y; a0h.z += vh.z; a0h.w += vh.w;
                c0 += 8;
            }
            if (has1 && c1 < e1) {
                int sr = csr[c1];
                float4 vl = T4[(size_t)sr * 16 + fl * 2];
                float4 vh = T4[(size_t)sr * 16 + fl * 2 + 1];
                a1l.x += vl.x; a1l.y += vl.y; a1l.z += vl.z; a1l.w += vl.w;
                a1h.x += vh.x; a1h.y += vh.y; a1h.z += vh.z; a1h.w += vh.w;
                c1 += 8;
            }
        }

        // reduce across the 8 slots (lane bits 3,4,5)
        #pragma unroll
        for (int m = 8; m <= 32; m <<= 1) {
            a0l.x += __shfl_xor(a0l.x, m, 64); a0l.y += __shfl_xor(a0l.y, m, 64);
            a0l.z += __shfl_xor(a0l.z, m, 64); a0l.w += __shfl_xor(a0l.w, m, 64);
            a0h.x += __shfl_xor(a0h.x, m, 64); a0h.y += __shfl_xor(a0h.y, m, 64);
            a0h.z += __shfl_xor(a0h.z, m, 64); a0h.w += __shfl_xor(a0h.w, m, 64);
            a1l.x += __shfl_xor(a1l.x, m, 64); a1l.y += __shfl_xor(a1l.y, m, 64);
            a1l.z += __shfl_xor(a1l.z, m, 64); a1l.w += __shfl_xor(a1l.w, m, 64);
            a1h.x += __shfl_xor(a1h.x, m, 64); a1h.y += __shfl_xor(a1h.y, m, 64);
            a1h.z += __shfl_xor(a1h.z, m, 64); a1h.w += __shfl_xor(a1h.w, m, 64);
        }

        // matvec: feature k owned by lane (k>>3), component (k&7)
        float acc0 = 0.f, acc1 = 0.f;
        #pragma unroll
        for (int k = 0; k < 64; ++k) {
            const int c = k & 7, sl = k >> 3;
            float comp0 = c == 0 ? a0l.x : c == 1 ? a0l.y : c == 2 ? a0l.z : c == 3 ? a0l.w
                        : c == 4 ? a0h.x : c == 5 ? a0h.y : c == 6 ? a0h.z : a0h.w;
            float comp1 = c == 0 ? a1l.x : c == 1 ? a1l.y : c == 2 ? a1l.z : c == 3 ? a1l.w
                        : c == 4 ? a1h.x : c == 5 ? a1h.y : c == 6 ? a1h.z : a1h.w;
            float wk = Wl[k * 64 + lane];
            acc0 = fmaf(__shfl(comp0, sl, 64), wk, acc0);
            acc1 = fmaf(__shfl(comp1, sl, 64), wk, acc1);
        }
        float y0 = dinv[i0] * acc0 + bv;
        Y[(size_t)i0 * 64 + lane] = y0;
        s += (double)y0; sq += (double)y0 * (double)y0;
        if (has1) {
            float y1v = dinv[i1] * acc1 + bv;
            Y[(size_t)i1 * 64 + lane] = y1v;
            s += (double)y1v; sq += (double)y1v * (double)y1v;
        }
    }

    ls[threadIdx.x] = s; lq[threadIdx.x] = sq;
    __syncthreads();
    if (threadIdx.x < 64) {
        double ts = ls[threadIdx.x] + ls[threadIdx.x + 64] + ls[threadIdx.x + 128] + ls[threadIdx.x + 192];
        double tq = lq[threadIdx.x] + lq[threadIdx.x + 64] + lq[threadIdx.x + 128] + lq[threadIdx.x + 192];
        atomicAdd(&stats_out[threadIdx.x], ts);
        atomicAdd(&stats_out[64 + threadIdx.x], tq);
    }
}

// ---- head: hs3[row] = (relu(BN(y2[row])) . W3) * dinv[row] ----
__global__ void head_w3(const float* __restrict__ Y, const double* __restrict__ stats,
                        const float* __restrict__ g, const float* __restrict__ bt,
                        const float* __restrict__ W3, const float* __restrict__ dinv,
                        float* __restrict__ hs3, int n) {
    int lane = threadIdx.x & 63;
    double mean = stats[lane] / n;
    double var  = stats[64 + lane] / n - mean * mean;
    float scale = (float)(1.0 / sqrt(var + 1e-5)) * g[lane];
    float shift = bt[lane] - (float)mean * scale;
    float w = W3[lane];
    int wave  = (blockIdx.x * blockDim.x + threadIdx.x) >> 6;
    int nwave = (gridDim.x * blockDim.x) >> 6;
    for (int row = wave; row < n; row += nwave) {
        float v = fmaxf(Y[(size_t)row * 64 + lane] * scale + shift, 0.f) * w;
        #pragma unroll
        for (int o = 32; o > 0; o >>= 1) v += __shfl_down(v, o, 64);
        if (lane == 0) hs3[row] = v * dinv[row];
    }
}

// ---- layer-3 aggregation: wave per node, lane-parallel edge gather ----
__global__ void agg1(const float* __restrict__ hs3, const int* __restrict__ csr,
                     const int* __restrict__ off, const float* __restrict__ dinv,
                     const float* __restrict__ b3, float* __restrict__ out, int n) {
    float b = b3[0];
    int lane  = threadIdx.x & 63;
    int wave  = (blockIdx.x * blockDim.x + threadIdx.x) >> 6;
    int nwave = (gridDim.x * blockDim.x) >> 6;
    for (int i = wave; i < n; i += nwave) {
        int beg = off[i], end = off[i + 1];
        float acc = 0.f;
        for (int e = beg + lane; e < end; e += 64) acc += hs3[csr[e]];
        #pragma unroll
        for (int o = 32; o > 0; o >>= 1) acc += __shfl_down(acc, o, 64);
        if (lane == 0) out[i] = dinv[i] * (acc + hs3[i]) + b;
    }
}

extern "C" void kernel_launch(void* const* d_in, const int* in_sizes, int n_in,
                              void* d_out, int out_size, void* d_ws, size_t ws_size,
                              hipStream_t stream) {
    const float* x   = (const float*)d_in[0];
    const float* W1  = (const float*)d_in[1];
    const float* b1  = (const float*)d_in[2];
    const float* g1  = (const float*)d_in[3];
    const float* bt1 = (const float*)d_in[4];
    const float* W2  = (const float*)d_in[5];
    const float* b2  = (const float*)d_in[6];
    const float* g2  = (const float*)d_in[7];
    const float* bt2 = (const float*)d_in[8];
    const float* W3  = (const float*)d_in[9];
    const float* b3  = (const float*)d_in[10];
    const int*  edge = (const int*)d_in[11];

    int n = in_sizes[0] / 64;
    int E = in_sizes[11] / 2;
    const int* src = edge;
    const int* dst = edge + E;
    float* out = (float*)d_out;
    int nblk  = (n + 255) / 256;      // 196
    int nbuck = (n + 255) / 256;      // bucket = dst >> 8
    int cap   = ((E / nbuck) * 5 / 4 + 63) & ~63;   // ~10240, overflow-safe

    // ---- workspace ----
    char* p = (char*)d_ws;
    double* stats = (double*)p;            p += 256 * sizeof(double);
    float* dinv   = (float*)p;             p += ((n + 63) & ~63) * sizeof(float);
    int* degi     = (int*)p;               p += ((n + 63) & ~63) * sizeof(int);
    int* off      = (int*)p;               p += ((n + 64) & ~63) * sizeof(int);
    int* part     = (int*)p;               p += 256 * sizeof(int);
    int* gcur     = (int*)p;               p += 256 * sizeof(int);
    int* csr      = (int*)p;               p += (size_t)E * sizeof(int);
    float* A      = (float*)p;             p += (size_t)n * 64 * sizeof(float);  // T1/T2
    float* B      = (float*)p;             p += (size_t)n * 64 * sizeof(float);  // Y1/Y2
    float* hs3    = (float*)p;             /* n floats */
    unsigned* binned = (unsigned*)A;       // aliases A (dead before prescale)

    hipMemsetAsync(gcur, 0, 256 * sizeof(int), stream);
    hipMemsetAsync(stats, 0, 256 * sizeof(double), stream);

    // CSR build (locality-staged)
    bin_edges<<<nbuck, 256, 0, stream>>>(src, dst, gcur, binned, E, nbuck, cap);
    bucket_deg<<<nbuck, 256, 0, stream>>>(binned, gcur, degi, nbuck, cap, n);
    scan_part<<<nblk, 256, 0, stream>>>(degi, part, n);
    scan_root<<<1, 256, 0, stream>>>(part, nblk);
    scan_write<<<nblk, 256, 0, stream>>>(degi, part, off, dinv, n);
    csr_fill_b<<<nbuck, 256, 0, stream>>>(binned, gcur, off, csr, nbuck, cap, n);

    // layer 1: T1 = x*dinv ; y1 = dinv*(gather-sum T1)@W1 + b1
    prescale<<<1024, 256, 0, stream>>>(x, dinv, A, n);
    agg_mm<<<2048, 256, 0, stream>>>((const float4*)A, csr, off, dinv, W1, b1,
                                     stats, B, n);
    // layer 2: T2 = relu(BN1(y1))*dinv ; y2 = dinv*(gather-sum T2)@W2 + b2
    bnrelu_scale<<<1024, 256, 0, stream>>>(B, stats, g1, bt1, dinv, A, n);
    agg_mm<<<2048, 256, 0, stream>>>((const float4*)A, csr, off, dinv, W2, b2,
                                     stats + 128, B, n);
    // layer 3
    head_w3<<<2048, 256, 0, stream>>>(B, stats + 128, g2, bt2, W3, dinv, hs3, n);
    agg1<<<2048, 256, 0, stream>>>(hs3, csr, off, dinv, b3, out, n);
}

// Round 9
// 428.543 us; speedup vs baseline: 1.1650x; 1.1650x over previous
//
#include <hip/hip_runtime.h>
#include <hip/hip_bf16.h>

// GCN, CSR-gather, pre-transformed tables.
//   T = f(X)*dinv ; y[d] = dinv[d]*(sum_{s in N(d)} T[s] + T[d])@W + b
// CSR fill is WINDOWED: block-group w handles dst in [n*w/8, n*(w+1)/8) so csr
// stores stay in a ~0.8MB L2-resident window (full-line writebacks, ~6 MB total
// instead of 103 MB of partial-line write-through). Edge list re-reads hit L3.

// ---- degree count (global int atomics: ~5us, not a bottleneck) ----
__global__ void deg_count(const int* __restrict__ dst, int* __restrict__ degi, int E) {
    int tid = blockIdx.x * blockDim.x + threadIdx.x;
    int stride = gridDim.x * blockDim.x;
    for (int e = tid; e < E; e += stride) atomicAdd(&degi[dst[e]], 1);
}

__global__ void scan_part(const int* __restrict__ degi, int* __restrict__ part, int n) {
    __shared__ int ls[256];
    int i = blockIdx.x * 256 + threadIdx.x;
    ls[threadIdx.x] = (i < n) ? degi[i] : 0;
    __syncthreads();
    for (int o = 128; o > 0; o >>= 1) {
        if (threadIdx.x < o) ls[threadIdx.x] += ls[threadIdx.x + o];
        __syncthreads();
    }
    if (threadIdx.x == 0) part[blockIdx.x] = ls[0];
}

__global__ void scan_root(int* __restrict__ part, int nblk) {   // nblk <= 256
    __shared__ int ls[256];
    int t = threadIdx.x;
    int v = (t < nblk) ? part[t] : 0;
    ls[t] = v;
    __syncthreads();
    for (int o = 1; o < 256; o <<= 1) {
        int u = (t >= o) ? ls[t - o] : 0;
        __syncthreads();
        ls[t] += u;
        __syncthreads();
    }
    if (t < nblk) part[t] = ls[t] - v;   // exclusive
}

__global__ void scan_write(const int* __restrict__ degi, const int* __restrict__ part,
                           int* __restrict__ off, int* __restrict__ cur,
                           float* __restrict__ dinv, int n) {
    __shared__ int ls[256];
    int t = threadIdx.x, i = blockIdx.x * 256 + t;
    int d = (i < n) ? degi[i] : 0;
    ls[t] = d;
    __syncthreads();
    for (int o = 1; o < 256; o <<= 1) {
        int u = (t >= o) ? ls[t - o] : 0;
        __syncthreads();
        ls[t] += u;
        __syncthreads();
    }
    if (i < n) {
        int o0 = part[blockIdx.x] + ls[t] - d;
        off[i] = o0;
        cur[i] = o0;
        dinv[i] = rsqrtf((float)d + 1.0f);   // +1 self loop
        if (i == n - 1) off[n] = o0 + d;
    }
}

// ---- windowed CSR fill: block-group (blockIdx&7) owns one n/8 dst-window ----
__global__ void csr_fill_x(const int* __restrict__ src, const int* __restrict__ dst,
                           int* __restrict__ cur, int* __restrict__ csr, int E, int n) {
    int w = blockIdx.x & 7;
    int lo = (int)(((long long)n * w) >> 3);
    int hi = (int)(((long long)n * (w + 1)) >> 3);
    int tid = (blockIdx.x >> 3) * blockDim.x + threadIdx.x;
    int stride = (gridDim.x >> 3) * blockDim.x;
    for (int e = tid; e < E; e += stride) {
        int d = dst[e];
        if (d >= lo && d < hi) {
            int p = atomicAdd(&cur[d], 1);
            csr[p] = src[e];
        }
    }
}

// ---- T1 = x * dinv ----
__global__ void prescale(const float* __restrict__ x, const float* __restrict__ dinv,
                         float* __restrict__ T, int n) {
    int tid = blockIdx.x * blockDim.x + threadIdx.x;
    int stride = gridDim.x * blockDim.x;
    int total = n * 16;            // float4 count
    const float4* x4 = (const float4*)x;
    float4* T4 = (float4*)T;
    for (int i = tid; i < total; i += stride) {
        float4 v = x4[i];
        float dv = dinv[i >> 4];
        v.x *= dv; v.y *= dv; v.z *= dv; v.w *= dv;
        T4[i] = v;
    }
}

// ---- T2 = relu(BN(y)) * dinv ----
__global__ void bnrelu_scale(const float* __restrict__ Y, const double* __restrict__ stats,
                             const float* __restrict__ g, const float* __restrict__ bt,
                             const float* __restrict__ dinv, float* __restrict__ T, int n) {
    int f = threadIdx.x & 63;
    double mean = stats[f] / n;
    double var  = stats[64 + f] / n - mean * mean;
    float scale = (float)(1.0 / sqrt(var + 1e-5)) * g[f];
    float shift = bt[f] - (float)mean * scale;
    int tid = blockIdx.x * blockDim.x + threadIdx.x;
    int stride = gridDim.x * blockDim.x;   // multiple of 64
    for (int i = tid; i < n * 64; i += stride) {
        float v = fmaxf(Y[i] * scale + shift, 0.f);
        T[i] = v * dinv[i >> 6];
    }
}

// ---- fused layer: pure gather-sum -> @W -> *dinv + b -> stats ----
__global__ __launch_bounds__(256) void agg_mm(
        const float4* __restrict__ T4, const int* __restrict__ csr,
        const int* __restrict__ off, const float* __restrict__ dinv,
        const float* __restrict__ W, const float* __restrict__ bias,
        double* __restrict__ stats_out, float* __restrict__ Y, int n) {
    __shared__ float Wl[64 * 64];
    __shared__ double ls[256], lq[256];
    for (int t = threadIdx.x; t < 64 * 64; t += blockDim.x) Wl[t] = W[t];

    int lane = threadIdx.x & 63;
    int slot = lane >> 3;      // 8 edge slots
    int fl   = lane & 7;       // floats 8*fl .. 8*fl+7 (two float4)
    float bv = bias[lane];
    __syncthreads();

    int wave  = (blockIdx.x * blockDim.x + threadIdx.x) >> 6;
    int nwave = (gridDim.x * blockDim.x) >> 6;
    double s = 0.0, sq = 0.0;

    for (int i0 = wave; i0 < n; i0 += 2 * nwave) {
        int i1 = i0 + nwave;
        bool has1 = (i1 < n);
        int b0 = off[i0], e0 = off[i0 + 1];
        int b1 = 0, e1 = 0;
        if (has1) { b1 = off[i1]; e1 = off[i1 + 1]; }

        float4 a0l = {0,0,0,0}, a0h = {0,0,0,0};
        float4 a1l = {0,0,0,0}, a1h = {0,0,0,0};
        if (slot == 0) {                       // self term in slot 0 only
            a0l = T4[(size_t)i0 * 16 + fl * 2];
            a0h = T4[(size_t)i0 * 16 + fl * 2 + 1];
            if (has1) {
                a1l = T4[(size_t)i1 * 16 + fl * 2];
                a1h = T4[(size_t)i1 * 16 + fl * 2 + 1];
            }
        }

        int c0 = b0 + slot, c1 = b1 + slot;
        while (c0 < e0 || (has1 && c1 < e1)) {
            if (c0 < e0) {
                int sr = csr[c0];
                float4 vl = T4[(size_t)sr * 16 + fl * 2];
                float4 vh = T4[(size_t)sr * 16 + fl * 2 + 1];
                a0l.x += vl.x; a0l.y += vl.y; a0l.z += vl.z; a0l.w += vl.w;
                a0h.x += vh.x; a0h.y += vh.y; a0h.z += vh.z; a0h.w += vh.w;
                c0 += 8;
            }
            if (has1 && c1 < e1) {
                int sr = csr[c1];
                float4 vl = T4[(size_t)sr * 16 + fl * 2];
                float4 vh = T4[(size_t)sr * 16 + fl * 2 + 1];
                a1l.x += vl.x; a1l.y += vl.y; a1l.z += vl.z; a1l.w += vl.w;
                a1h.x += vh.x; a1h.y += vh.y; a1h.z += vh.z; a1h.w += vh.w;
                c1 += 8;
            }
        }

        // reduce across the 8 slots (lane bits 3,4,5)
        #pragma unroll
        for (int m = 8; m <= 32; m <<= 1) {
            a0l.x += __shfl_xor(a0l.x, m, 64); a0l.y += __shfl_xor(a0l.y, m, 64);
            a0l.z += __shfl_xor(a0l.z, m, 64); a0l.w += __shfl_xor(a0l.w, m, 64);
            a0h.x += __shfl_xor(a0h.x, m, 64); a0h.y += __shfl_xor(a0h.y, m, 64);
            a0h.z += __shfl_xor(a0h.z, m, 64); a0h.w += __shfl_xor(a0h.w, m, 64);
            a1l.x += __shfl_xor(a1l.x, m, 64); a1l.y += __shfl_xor(a1l.y, m, 64);
            a1l.z += __shfl_xor(a1l.z, m, 64); a1l.w += __shfl_xor(a1l.w, m, 64);
            a1h.x += __shfl_xor(a1h.x, m, 64); a1h.y += __shfl_xor(a1h.y, m, 64);
            a1h.w += __shfl_xor(a1h.w, m, 64); a1h.z += __shfl_xor(a1h.z, m, 64);
        }

        // matvec: feature k owned by lane (k>>3), component (k&7)
        float acc0 = 0.f, acc1 = 0.f;
        #pragma unroll
        for (int k = 0; k < 64; ++k) {
            const int c = k & 7, sl = k >> 3;
            float comp0 = c == 0 ? a0l.x : c == 1 ? a0l.y : c == 2 ? a0l.z : c == 3 ? a0l.w
                        : c == 4 ? a0h.x : c == 5 ? a0h.y : c == 6 ? a0h.z : a0h.w;
            float comp1 = c == 0 ? a1l.x : c == 1 ? a1l.y : c == 2 ? a1l.z : c == 3 ? a1l.w
                        : c == 4 ? a1h.x : c == 5 ? a1h.y : c == 6 ? a1h.z : a1h.w;
            float wk = Wl[k * 64 + lane];
            acc0 = fmaf(__shfl(comp0, sl, 64), wk, acc0);
            acc1 = fmaf(__shfl(comp1, sl, 64), wk, acc1);
        }
        float y0 = dinv[i0] * acc0 + bv;
        Y[(size_t)i0 * 64 + lane] = y0;
        s += (double)y0; sq += (double)y0 * (double)y0;
        if (has1) {
            float y1v = dinv[i1] * acc1 + bv;
            Y[(size_t)i1 * 64 + lane] = y1v;
            s += (double)y1v; sq += (double)y1v * (double)y1v;
        }
    }

    ls[threadIdx.x] = s; lq[threadIdx.x] = sq;
    __syncthreads();
    if (threadIdx.x < 64) {
        double ts = ls[threadIdx.x] + ls[threadIdx.x + 64] + ls[threadIdx.x + 128] + ls[threadIdx.x + 192];
        double tq = lq[threadIdx.x] + lq[threadIdx.x + 64] + lq[threadIdx.x + 128] + lq[threadIdx.x + 192];
        atomicAdd(&stats_out[threadIdx.x], ts);
        atomicAdd(&stats_out[64 + threadIdx.x], tq);
    }
}

// ---- head: hs3[row] = (relu(BN(y2[row])) . W3) * dinv[row] ----
__global__ void head_w3(const float* __restrict__ Y, const double* __restrict__ stats,
                        const float* __restrict__ g, const float* __restrict__ bt,
                        const float* __restrict__ W3, const float* __restrict__ dinv,
                        float* __restrict__ hs3, int n) {
    int lane = threadIdx.x & 63;
    double mean = stats[lane] / n;
    double var  = stats[64 + lane] / n - mean * mean;
    float scale = (float)(1.0 / sqrt(var + 1e-5)) * g[lane];
    float shift = bt[lane] - (float)mean * scale;
    float w = W3[lane];
    int wave  = (blockIdx.x * blockDim.x + threadIdx.x) >> 6;
    int nwave = (gridDim.x * blockDim.x) >> 6;
    for (int row = wave; row < n; row += nwave) {
        float v = fmaxf(Y[(size_t)row * 64 + lane] * scale + shift, 0.f) * w;
        #pragma unroll
        for (int o = 32; o > 0; o >>= 1) v += __shfl_down(v, o, 64);
        if (lane == 0) hs3[row] = v * dinv[row];
    }
}

// ---- layer-3 aggregation: wave per node, lane-parallel edge gather ----
__global__ void agg1(const float* __restrict__ hs3, const int* __restrict__ csr,
                     const int* __restrict__ off, const float* __restrict__ dinv,
                     const float* __restrict__ b3, float* __restrict__ out, int n) {
    float b = b3[0];
    int lane  = threadIdx.x & 63;
    int wave  = (blockIdx.x * blockDim.x + threadIdx.x) >> 6;
    int nwave = (gridDim.x * blockDim.x) >> 6;
    for (int i = wave; i < n; i += nwave) {
        int beg = off[i], end = off[i + 1];
        float acc = 0.f;
        for (int e = beg + lane; e < end; e += 64) acc += hs3[csr[e]];
        #pragma unroll
        for (int o = 32; o > 0; o >>= 1) acc += __shfl_down(acc, o, 64);
        if (lane == 0) out[i] = dinv[i] * (acc + hs3[i]) + b;
    }
}

extern "C" void kernel_launch(void* const* d_in, const int* in_sizes, int n_in,
                              void* d_out, int out_size, void* d_ws, size_t ws_size,
                              hipStream_t stream) {
    const float* x   = (const float*)d_in[0];
    const float* W1  = (const float*)d_in[1];
    const float* b1  = (const float*)d_in[2];
    const float* g1  = (const float*)d_in[3];
    const float* bt1 = (const float*)d_in[4];
    const float* W2  = (const float*)d_in[5];
    const float* b2  = (const float*)d_in[6];
    const float* g2  = (const float*)d_in[7];
    const float* bt2 = (const float*)d_in[8];
    const float* W3  = (const float*)d_in[9];
    const float* b3  = (const float*)d_in[10];
    const int*  edge = (const int*)d_in[11];

    int n = in_sizes[0] / 64;
    int E = in_sizes[11] / 2;
    const int* src = edge;
    const int* dst = edge + E;
    float* out = (float*)d_out;
    int nblk = (n + 255) / 256;

    // ---- workspace ----
    char* p = (char*)d_ws;
    double* stats = (double*)p;            p += 256 * sizeof(double);  // L1:0..127, L2:128..255
    float* dinv   = (float*)p;             p += ((n + 63) & ~63) * sizeof(float);
    int* degi     = (int*)p;               p += ((n + 63) & ~63) * sizeof(int);
    int* off      = (int*)p;               p += ((n + 64) & ~63) * sizeof(int);
    int* cur      = (int*)p;               p += ((n + 63) & ~63) * sizeof(int);
    int* part     = (int*)p;               p += 256 * sizeof(int);
    int* csr      = (int*)p;               p += (size_t)E * sizeof(int);
    float* A      = (float*)p;             p += (size_t)n * 64 * sizeof(float);  // T1/T2
    float* B      = (float*)p;             p += (size_t)n * 64 * sizeof(float);  // Y1/Y2
    float* hs3    = (float*)p;             /* n floats */

    hipMemsetAsync(degi, 0, n * sizeof(int), stream);
    hipMemsetAsync(stats, 0, 256 * sizeof(double), stream);

    // CSR build
    deg_count<<<2048, 256, 0, stream>>>(dst, degi, E);
    scan_part<<<nblk, 256, 0, stream>>>(degi, part, n);
    scan_root<<<1, 256, 0, stream>>>(part, nblk);
    scan_write<<<nblk, 256, 0, stream>>>(degi, part, off, cur, dinv, n);
    csr_fill_x<<<2048, 256, 0, stream>>>(src, dst, cur, csr, E, n);

    // layer 1: T1 = x*dinv ; y1 = dinv*(gather-sum T1)@W1 + b1
    prescale<<<1024, 256, 0, stream>>>(x, dinv, A, n);
    agg_mm<<<2048, 256, 0, stream>>>((const float4*)A, csr, off, dinv, W1, b1,
                                     stats, B, n);
    // layer 2: T2 = relu(BN1(y1))*dinv ; y2 = dinv*(gather-sum T2)@W2 + b2
    bnrelu_scale<<<1024, 256, 0, stream>>>(B, stats, g1, bt1, dinv, A, n);
    agg_mm<<<2048, 256, 0, stream>>>((const float4*)A, csr, off, dinv, W2, b2,
                                     stats + 128, B, n);
    // layer 3
    head_w3<<<2048, 256, 0, stream>>>(B, stats + 128, g2, bt2, W3, dinv, hs3, n);
    agg1<<<2048, 256, 0, stream>>>(hs3, csr, off, dinv, b3, out, n);
}

// Round 10
// 379.498 us; speedup vs baseline: 1.3155x; 1.1292x over previous
//
#include <hip/hip_runtime.h>
#include <hip/hip_bf16.h>

// GCN, CSR-gather, pre-transformed tables.
//   T = f(X)*dinv ; y[d] = dinv[d]*(sum_{s in N(d)} T[s] + T[d])@W + b
// agg_mm: ONE node per wave, 8 edge-slots x float8/lane, unroll-2 edge loop.
// VGPR diet (<64) to double wave residency vs dual-stream version (80 VGPR).
// CSR fill is windowed (blockIdx&7 -> n/8 dst-window) for L2-local writes.

// ---- degree count ----
__global__ void deg_count(const int* __restrict__ dst, int* __restrict__ degi, int E) {
    int tid = blockIdx.x * blockDim.x + threadIdx.x;
    int stride = gridDim.x * blockDim.x;
    for (int e = tid; e < E; e += stride) atomicAdd(&degi[dst[e]], 1);
}

__global__ void scan_part(const int* __restrict__ degi, int* __restrict__ part, int n) {
    __shared__ int ls[256];
    int i = blockIdx.x * 256 + threadIdx.x;
    ls[threadIdx.x] = (i < n) ? degi[i] : 0;
    __syncthreads();
    for (int o = 128; o > 0; o >>= 1) {
        if (threadIdx.x < o) ls[threadIdx.x] += ls[threadIdx.x + o];
        __syncthreads();
    }
    if (threadIdx.x == 0) part[blockIdx.x] = ls[0];
}

__global__ void scan_root(int* __restrict__ part, int nblk) {   // nblk <= 256
    __shared__ int ls[256];
    int t = threadIdx.x;
    int v = (t < nblk) ? part[t] : 0;
    ls[t] = v;
    __syncthreads();
    for (int o = 1; o < 256; o <<= 1) {
        int u = (t >= o) ? ls[t - o] : 0;
        __syncthreads();
        ls[t] += u;
        __syncthreads();
    }
    if (t < nblk) part[t] = ls[t] - v;   // exclusive
}

__global__ void scan_write(const int* __restrict__ degi, const int* __restrict__ part,
                           int* __restrict__ off, int* __restrict__ cur,
                           float* __restrict__ dinv, int n) {
    __shared__ int ls[256];
    int t = threadIdx.x, i = blockIdx.x * 256 + t;
    int d = (i < n) ? degi[i] : 0;
    ls[t] = d;
    __syncthreads();
    for (int o = 1; o < 256; o <<= 1) {
        int u = (t >= o) ? ls[t - o] : 0;
        __syncthreads();
        ls[t] += u;
        __syncthreads();
    }
    if (i < n) {
        int o0 = part[blockIdx.x] + ls[t] - d;
        off[i] = o0;
        cur[i] = o0;
        dinv[i] = rsqrtf((float)d + 1.0f);   // +1 self loop
        if (i == n - 1) off[n] = o0 + d;
    }
}

// ---- windowed CSR fill: block-group (blockIdx&7) owns one n/8 dst-window ----
__global__ void csr_fill_x(const int* __restrict__ src, const int* __restrict__ dst,
                           int* __restrict__ cur, int* __restrict__ csr, int E, int n) {
    int w = blockIdx.x & 7;
    int lo = (int)(((long long)n * w) >> 3);
    int hi = (int)(((long long)n * (w + 1)) >> 3);
    int tid = (blockIdx.x >> 3) * blockDim.x + threadIdx.x;
    int stride = (gridDim.x >> 3) * blockDim.x;
    for (int e = tid; e < E; e += stride) {
        int d = dst[e];
        if (d >= lo && d < hi) {
            int p = atomicAdd(&cur[d], 1);
            csr[p] = src[e];
        }
    }
}

// ---- T1 = x * dinv ----
__global__ void prescale(const float* __restrict__ x, const float* __restrict__ dinv,
                         float* __restrict__ T, int n) {
    int tid = blockIdx.x * blockDim.x + threadIdx.x;
    int stride = gridDim.x * blockDim.x;
    int total = n * 16;            // float4 count
    const float4* x4 = (const float4*)x;
    float4* T4 = (float4*)T;
    for (int i = tid; i < total; i += stride) {
        float4 v = x4[i];
        float dv = dinv[i >> 4];
        v.x *= dv; v.y *= dv; v.z *= dv; v.w *= dv;
        T4[i] = v;
    }
}

// ---- T2 = relu(BN(y)) * dinv ----
__global__ void bnrelu_scale(const float* __restrict__ Y, const double* __restrict__ stats,
                             const float* __restrict__ g, const float* __restrict__ bt,
                             const float* __restrict__ dinv, float* __restrict__ T, int n) {
    int f = threadIdx.x & 63;
    double mean = stats[f] / n;
    double var  = stats[64 + f] / n - mean * mean;
    float scale = (float)(1.0 / sqrt(var + 1e-5)) * g[f];
    float shift = bt[f] - (float)mean * scale;
    int tid = blockIdx.x * blockDim.x + threadIdx.x;
    int stride = gridDim.x * blockDim.x;   // multiple of 64
    for (int i = tid; i < n * 64; i += stride) {
        float v = fmaxf(Y[i] * scale + shift, 0.f);
        T[i] = v * dinv[i >> 6];
    }
}

// ---- fused layer: pure gather-sum -> @W -> *dinv + b -> stats ----
__global__ __launch_bounds__(256) void agg_mm(
        const float4* __restrict__ T4, const int* __restrict__ csr,
        const int* __restrict__ off, const float* __restrict__ dinv,
        const float* __restrict__ W, const float* __restrict__ bias,
        double* __restrict__ stats_out, float* __restrict__ Y, int n) {
    __shared__ float Wl[64 * 64];
    __shared__ double ls[256], lq[256];
    for (int t = threadIdx.x; t < 64 * 64; t += blockDim.x) Wl[t] = W[t];

    int lane = threadIdx.x & 63;
    int slot = lane >> 3;      // 8 edge slots
    int fl   = lane & 7;       // floats 8*fl .. 8*fl+7 (two float4)
    float bv = bias[lane];
    __syncthreads();

    int wave  = (blockIdx.x * blockDim.x + threadIdx.x) >> 6;
    int nwave = (gridDim.x * blockDim.x) >> 6;
    double s = 0.0, sq = 0.0;

    for (int i = wave; i < n; i += nwave) {
        int beg = off[i], end = off[i + 1];
        float dv = dinv[i];

        float4 al = {0,0,0,0}, ah = {0,0,0,0};
        if (slot == 0) {                       // self term in slot 0 only
            al = T4[(size_t)i * 16 + fl * 2];
            ah = T4[(size_t)i * 16 + fl * 2 + 1];
            al.x *= dv; al.y *= dv; al.z *= dv; al.w *= dv;
            ah.x *= dv; ah.y *= dv; ah.z *= dv; ah.w *= dv;
        }
        // NOTE: T is pre-scaled, but self term needs dv too -- T[i] already
        // includes dinv[i]; multiplying again would be wrong. Undo:
        if (slot == 0) {
            float r = 1.0f;   // placeholder to keep structure; corrected below
            (void)r;
        }

        // self term correction: T[i] is already x[i]*dinv[i]; the extra *dv
        // above was an error -- recompute cleanly:
        if (slot == 0) {
            al = T4[(size_t)i * 16 + fl * 2];
            ah = T4[(size_t)i * 16 + fl * 2 + 1];
        }

        #pragma unroll 2
        for (int c = beg + slot; c < end; c += 8) {
            int sr = csr[c];                    // 8-lane broadcast per slot
            float4 vl = T4[(size_t)sr * 16 + fl * 2];
            float4 vh = T4[(size_t)sr * 16 + fl * 2 + 1];
            al.x += vl.x; al.y += vl.y; al.z += vl.z; al.w += vl.w;
            ah.x += vh.x; ah.y += vh.y; ah.z += vh.z; ah.w += vh.w;
        }

        // reduce across the 8 slots (lane bits 3,4,5)
        #pragma unroll
        for (int m = 8; m <= 32; m <<= 1) {
            al.x += __shfl_xor(al.x, m, 64); al.y += __shfl_xor(al.y, m, 64);
            al.z += __shfl_xor(al.z, m, 64); al.w += __shfl_xor(al.w, m, 64);
            ah.x += __shfl_xor(ah.x, m, 64); ah.y += __shfl_xor(ah.y, m, 64);
            ah.z += __shfl_xor(ah.z, m, 64); ah.w += __shfl_xor(ah.w, m, 64);
        }

        // matvec: feature k owned by lane (k>>3), component (k&7)
        float acc = 0.f;
        #pragma unroll
        for (int k = 0; k < 64; ++k) {
            const int c = k & 7, sl = k >> 3;
            float comp = c == 0 ? al.x : c == 1 ? al.y : c == 2 ? al.z : c == 3 ? al.w
                       : c == 4 ? ah.x : c == 5 ? ah.y : c == 6 ? ah.z : ah.w;
            acc = fmaf(__shfl(comp, sl, 64), Wl[k * 64 + lane], acc);
        }
        float yv = dv * acc + bv;
        Y[(size_t)i * 64 + lane] = yv;
        s += (double)yv; sq += (double)yv * (double)yv;
    }

    ls[threadIdx.x] = s; lq[threadIdx.x] = sq;
    __syncthreads();
    if (threadIdx.x < 64) {
        double ts = ls[threadIdx.x] + ls[threadIdx.x + 64] + ls[threadIdx.x + 128] + ls[threadIdx.x + 192];
        double tq = lq[threadIdx.x] + lq[threadIdx.x + 64] + lq[threadIdx.x + 128] + lq[threadIdx.x + 192];
        atomicAdd(&stats_out[threadIdx.x], ts);
        atomicAdd(&stats_out[64 + threadIdx.x], tq);
    }
}

// ---- head: hs3[row] = (relu(BN(y2[row])) . W3) * dinv[row] ----
__global__ void head_w3(const float* __restrict__ Y, const double* __restrict__ stats,
                        const float* __restrict__ g, const float* __restrict__ bt,
                        const float* __restrict__ W3, const float* __restrict__ dinv,
                        float* __restrict__ hs3, int n) {
    int lane = threadIdx.x & 63;
    double mean = stats[lane] / n;
    double var  = stats[64 + lane] / n - mean * mean;
    float scale = (float)(1.0 / sqrt(var + 1e-5)) * g[lane];
    float shift = bt[lane] - (float)mean * scale;
    float w = W3[lane];
    int wave  = (blockIdx.x * blockDim.x + threadIdx.x) >> 6;
    int nwave = (gridDim.x * blockDim.x) >> 6;
    for (int row = wave; row < n; row += nwave) {
        float v = fmaxf(Y[(size_t)row * 64 + lane] * scale + shift, 0.f) * w;
        #pragma unroll
        for (int o = 32; o > 0; o >>= 1) v += __shfl_down(v, o, 64);
        if (lane == 0) hs3[row] = v * dinv[row];
    }
}

// ---- layer-3 aggregation: wave per node, lane-parallel edge gather ----
__global__ void agg1(const float* __restrict__ hs3, const int* __restrict__ csr,
                     const int* __restrict__ off, const float* __restrict__ dinv,
                     const float* __restrict__ b3, float* __restrict__ out, int n) {
    float b = b3[0];
    int lane  = threadIdx.x & 63;
    int wave  = (blockIdx.x * blockDim.x + threadIdx.x) >> 6;
    int nwave = (gridDim.x * blockDim.x) >> 6;
    for (int i = wave; i < n; i += nwave) {
        int beg = off[i], end = off[i + 1];
        float acc = 0.f;
        for (int e = beg + lane; e < end; e += 64) acc += hs3[csr[e]];
        #pragma unroll
        for (int o = 32; o > 0; o >>= 1) acc += __shfl_down(acc, o, 64);
        if (lane == 0) out[i] = dinv[i] * (acc + hs3[i]) + b;
    }
}

extern "C" void kernel_launch(void* const* d_in, const int* in_sizes, int n_in,
                              void* d_out, int out_size, void* d_ws, size_t ws_size,
                              hipStream_t stream) {
    const float* x   = (const float*)d_in[0];
    const float* W1  = (const float*)d_in[1];
    const float* b1  = (const float*)d_in[2];
    const float* g1  = (const float*)d_in[3];
    const float* bt1 = (const float*)d_in[4];
    const float* W2  = (const float*)d_in[5];
    const float* b2  = (const float*)d_in[6];
    const float* g2  = (const float*)d_in[7];
    const float* bt2 = (const float*)d_in[8];
    const float* W3  = (const float*)d_in[9];
    const float* b3  = (const float*)d_in[10];
    const int*  edge = (const int*)d_in[11];

    int n = in_sizes[0] / 64;
    int E = in_sizes[11] / 2;
    const int* src = edge;
    const int* dst = edge + E;
    float* out = (float*)d_out;
    int nblk = (n + 255) / 256;

    // ---- workspace ----
    char* p = (char*)d_ws;
    double* stats = (double*)p;            p += 256 * sizeof(double);  // L1:0..127, L2:128..255
    float* dinv   = (float*)p;             p += ((n + 63) & ~63) * sizeof(float);
    int* degi     = (int*)p;               p += ((n + 63) & ~63) * sizeof(int);
    int* off      = (int*)p;               p += ((n + 64) & ~63) * sizeof(int);
    int* cur      = (int*)p;               p += ((n + 63) & ~63) * sizeof(int);
    int* part     = (int*)p;               p += 256 * sizeof(int);
    int* csr      = (int*)p;               p += (size_t)E * sizeof(int);
    float* A      = (float*)p;             p += (size_t)n * 64 * sizeof(float);  // T1/T2
    float* B      = (float*)p;             p += (size_t)n * 64 * sizeof(float);  // Y1/Y2
    float* hs3    = (float*)p;             /* n floats */

    hipMemsetAsync(degi, 0, n * sizeof(int), stream);
    hipMemsetAsync(stats, 0, 256 * sizeof(double), stream);

    // CSR build
    deg_count<<<2048, 256, 0, stream>>>(dst, degi, E);
    scan_part<<<nblk, 256, 0, stream>>>(degi, part, n);
    scan_root<<<1, 256, 0, stream>>>(part, nblk);
    scan_write<<<nblk, 256, 0, stream>>>(degi, part, off, cur, dinv, n);
    csr_fill_x<<<2048, 256, 0, stream>>>(src, dst, cur, csr, E, n);

    // layer 1: T1 = x*dinv ; y1 = dinv*(gather-sum T1)@W1 + b1
    prescale<<<1024, 256, 0, stream>>>(x, dinv, A, n);
    agg_mm<<<2048, 256, 0, stream>>>((const float4*)A, csr, off, dinv, W1, b1,
                                     stats, B, n);
    // layer 2: T2 = relu(BN1(y1))*dinv ; y2 = dinv*(gather-sum T2)@W2 + b2
    bnrelu_scale<<<1024, 256, 0, stream>>>(B, stats, g1, bt1, dinv, A, n);
    agg_mm<<<2048, 256, 0, stream>>>((const float4*)A, csr, off, dinv, W2, b2,
                                     stats + 128, B, n);
    // layer 3
    head_w3<<<2048, 256, 0, stream>>>(B, stats + 128, g2, bt2, W3, dinv, hs3, n);
    agg1<<<2048, 256, 0, stream>>>(hs3, csr, off, dinv, b3, out, n);
}

// Round 11
// 364.330 us; speedup vs baseline: 1.3703x; 1.0416x over previous
//
#include <hip/hip_runtime.h>
#include <hip/hip_bf16.h>

// GCN, CSR-gather, pre-transformed BF16 tables:
//   T = bf16( f(X)*dinv )  (f = identity layer1, BN+ReLU layer2)
//   y[d] = dinv[d] * ( sum_{s in N(d)} T[s] + T[d] ) @ W + b   (f32 accum)
// agg_mm: one node/wave, 8 edge-slots x 8 bf16/lane (16B uint4), unroll-2.
// bf16 halves random-gather bytes AND fits T (6.4MB) mostly in per-XCD L2.

__device__ __forceinline__ unsigned f2bf(float f) {   // round-to-nearest-even
    unsigned u = __float_as_uint(f);
    return (u + 0x7FFFu + ((u >> 16) & 1u)) >> 16;
}
__device__ __forceinline__ float bflo(unsigned w) { return __uint_as_float(w << 16); }
__device__ __forceinline__ float bfhi(unsigned w) { return __uint_as_float(w & 0xFFFF0000u); }

// ---- degree count ----
__global__ void deg_count(const int* __restrict__ dst, int* __restrict__ degi, int E) {
    int tid = blockIdx.x * blockDim.x + threadIdx.x;
    int stride = gridDim.x * blockDim.x;
    for (int e = tid; e < E; e += stride) atomicAdd(&degi[dst[e]], 1);
}

__global__ void scan_part(const int* __restrict__ degi, int* __restrict__ part, int n) {
    __shared__ int ls[256];
    int i = blockIdx.x * 256 + threadIdx.x;
    ls[threadIdx.x] = (i < n) ? degi[i] : 0;
    __syncthreads();
    for (int o = 128; o > 0; o >>= 1) {
        if (threadIdx.x < o) ls[threadIdx.x] += ls[threadIdx.x + o];
        __syncthreads();
    }
    if (threadIdx.x == 0) part[blockIdx.x] = ls[0];
}

__global__ void scan_root(int* __restrict__ part, int nblk) {   // nblk <= 256
    __shared__ int ls[256];
    int t = threadIdx.x;
    int v = (t < nblk) ? part[t] : 0;
    ls[t] = v;
    __syncthreads();
    for (int o = 1; o < 256; o <<= 1) {
        int u = (t >= o) ? ls[t - o] : 0;
        __syncthreads();
        ls[t] += u;
        __syncthreads();
    }
    if (t < nblk) part[t] = ls[t] - v;   // exclusive
}

__global__ void scan_write(const int* __restrict__ degi, const int* __restrict__ part,
                           int* __restrict__ off, int* __restrict__ cur,
                           float* __restrict__ dinv, int n) {
    __shared__ int ls[256];
    int t = threadIdx.x, i = blockIdx.x * 256 + t;
    int d = (i < n) ? degi[i] : 0;
    ls[t] = d;
    __syncthreads();
    for (int o = 1; o < 256; o <<= 1) {
        int u = (t >= o) ? ls[t - o] : 0;
        __syncthreads();
        ls[t] += u;
        __syncthreads();
    }
    if (i < n) {
        int o0 = part[blockIdx.x] + ls[t] - d;
        off[i] = o0;
        cur[i] = o0;
        dinv[i] = rsqrtf((float)d + 1.0f);   // +1 self loop
        if (i == n - 1) off[n] = o0 + d;
    }
}

// ---- windowed CSR fill: block-group (blockIdx&7) owns one n/8 dst-window ----
__global__ void csr_fill_x(const int* __restrict__ src, const int* __restrict__ dst,
                           int* __restrict__ cur, int* __restrict__ csr, int E, int n) {
    int w = blockIdx.x & 7;
    int lo = (int)(((long long)n * w) >> 3);
    int hi = (int)(((long long)n * (w + 1)) >> 3);
    int tid = (blockIdx.x >> 3) * blockDim.x + threadIdx.x;
    int stride = (gridDim.x >> 3) * blockDim.x;
    for (int e = tid; e < E; e += stride) {
        int d = dst[e];
        if (d >= lo && d < hi) {
            int p = atomicAdd(&cur[d], 1);
            csr[p] = src[e];
        }
    }
}

// ---- T1 = bf16(x * dinv); thread per u32 (feature pair) ----
__global__ void prescale(const float* __restrict__ x, const float* __restrict__ dinv,
                         unsigned* __restrict__ T, int n) {
    int tid = blockIdx.x * blockDim.x + threadIdx.x;
    int stride = gridDim.x * blockDim.x;
    int total = n * 32;   // u32 count (2 features each)
    const float2* x2 = (const float2*)x;
    for (int i = tid; i < total; i += stride) {
        float2 v = x2[i];
        float dv = dinv[i >> 5];
        T[i] = f2bf(v.x * dv) | (f2bf(v.y * dv) << 16);
    }
}

// ---- T2 = bf16(relu(BN(y)) * dinv); stride%32==0 so feature pair is fixed ----
__global__ void bnrelu_scale(const float* __restrict__ Y, const double* __restrict__ stats,
                             const float* __restrict__ g, const float* __restrict__ bt,
                             const float* __restrict__ dinv, unsigned* __restrict__ T, int n) {
    int jj = threadIdx.x & 31;            // u32 index within row
    int f0 = jj * 2, f1 = jj * 2 + 1;
    double m0 = stats[f0] / n, m1 = stats[f1] / n;
    double v0 = stats[64 + f0] / n - m0 * m0, v1 = stats[64 + f1] / n - m1 * m1;
    float sc0 = (float)(1.0 / sqrt(v0 + 1e-5)) * g[f0];
    float sc1 = (float)(1.0 / sqrt(v1 + 1e-5)) * g[f1];
    float sh0 = bt[f0] - (float)m0 * sc0;
    float sh1 = bt[f1] - (float)m1 * sc1;
    const float2* Y2 = (const float2*)Y;
    int tid = blockIdx.x * blockDim.x + threadIdx.x;
    int stride = gridDim.x * blockDim.x;   // multiple of 32
    for (int i = tid; i < n * 32; i += stride) {
        float2 y = Y2[i];
        float dv = dinv[i >> 5];
        float a = fmaxf(y.x * sc0 + sh0, 0.f) * dv;
        float b = fmaxf(y.y * sc1 + sh1, 0.f) * dv;
        T[i] = f2bf(a) | (f2bf(b) << 16);
    }
}

// ---- fused layer: bf16 gather-sum (f32 accum) -> @W -> *dinv + b -> stats ----
__global__ __launch_bounds__(256) void agg_mm(
        const uint4* __restrict__ Tb, const int* __restrict__ csr,
        const int* __restrict__ off, const float* __restrict__ dinv,
        const float* __restrict__ W, const float* __restrict__ bias,
        double* __restrict__ stats_out, float* __restrict__ Y, int n) {
    __shared__ float Wl[64 * 64];
    __shared__ double ls[256], lq[256];
    for (int t = threadIdx.x; t < 64 * 64; t += blockDim.x) Wl[t] = W[t];

    int lane = threadIdx.x & 63;
    int slot = lane >> 3;      // 8 edge slots
    int fl   = lane & 7;       // features 8*fl .. 8*fl+7  (one uint4 = 8 bf16)
    float bv = bias[lane];
    __syncthreads();

    int wave  = (blockIdx.x * blockDim.x + threadIdx.x) >> 6;
    int nwave = (gridDim.x * blockDim.x) >> 6;
    double s = 0.0, sq = 0.0;

    for (int i = wave; i < n; i += nwave) {
        int beg = off[i], end = off[i + 1];
        float dv = dinv[i];

        float4 al = {0,0,0,0}, ah = {0,0,0,0};
        if (slot == 0) {                       // self term in slot 0 only
            uint4 r = Tb[(size_t)i * 8 + fl];
            al.x = bflo(r.x); al.y = bfhi(r.x);
            al.z = bflo(r.y); al.w = bfhi(r.y);
            ah.x = bflo(r.z); ah.y = bfhi(r.z);
            ah.z = bflo(r.w); ah.w = bfhi(r.w);
        }

        #pragma unroll 2
        for (int c = beg + slot; c < end; c += 8) {
            int sr = csr[c];                    // 8-lane broadcast per slot
            uint4 r = Tb[(size_t)sr * 8 + fl];
            al.x += bflo(r.x); al.y += bfhi(r.x);
            al.z += bflo(r.y); al.w += bfhi(r.y);
            ah.x += bflo(r.z); ah.y += bfhi(r.z);
            ah.z += bflo(r.w); ah.w += bfhi(r.w);
        }

        // reduce across the 8 slots (lane bits 3,4,5)
        #pragma unroll
        for (int m = 8; m <= 32; m <<= 1) {
            al.x += __shfl_xor(al.x, m, 64); al.y += __shfl_xor(al.y, m, 64);
            al.z += __shfl_xor(al.z, m, 64); al.w += __shfl_xor(al.w, m, 64);
            ah.x += __shfl_xor(ah.x, m, 64); ah.y += __shfl_xor(ah.y, m, 64);
            ah.z += __shfl_xor(ah.z, m, 64); ah.w += __shfl_xor(ah.w, m, 64);
        }

        // matvec: feature k owned by lane (k>>3), component (k&7)
        float acc = 0.f;
        #pragma unroll
        for (int k = 0; k < 64; ++k) {
            const int c = k & 7, sl = k >> 3;
            float comp = c == 0 ? al.x : c == 1 ? al.y : c == 2 ? al.z : c == 3 ? al.w
                       : c == 4 ? ah.x : c == 5 ? ah.y : c == 6 ? ah.z : ah.w;
            acc = fmaf(__shfl(comp, sl, 64), Wl[k * 64 + lane], acc);
        }
        float yv = dv * acc + bv;
        Y[(size_t)i * 64 + lane] = yv;
        s += (double)yv; sq += (double)yv * (double)yv;
    }

    ls[threadIdx.x] = s; lq[threadIdx.x] = sq;
    __syncthreads();
    if (threadIdx.x < 64) {
        double ts = ls[threadIdx.x] + ls[threadIdx.x + 64] + ls[threadIdx.x + 128] + ls[threadIdx.x + 192];
        double tq = lq[threadIdx.x] + lq[threadIdx.x + 64] + lq[threadIdx.x + 128] + lq[threadIdx.x + 192];
        atomicAdd(&stats_out[threadIdx.x], ts);
        atomicAdd(&stats_out[64 + threadIdx.x], tq);
    }
}

// ---- head: hs3[row] = (relu(BN(y2[row])) . W3) * dinv[row] ----
__global__ void head_w3(const float* __restrict__ Y, const double* __restrict__ stats,
                        const float* __restrict__ g, const float* __restrict__ bt,
                        const float* __restrict__ W3, const float* __restrict__ dinv,
                        float* __restrict__ hs3, int n) {
    int lane = threadIdx.x & 63;
    double mean = stats[lane] / n;
    double var  = stats[64 + lane] / n - mean * mean;
    float scale = (float)(1.0 / sqrt(var + 1e-5)) * g[lane];
    float shift = bt[lane] - (float)mean * scale;
    float w = W3[lane];
    int wave  = (blockIdx.x * blockDim.x + threadIdx.x) >> 6;
    int nwave = (gridDim.x * blockDim.x) >> 6;
    for (int row = wave; row < n; row += nwave) {
        float v = fmaxf(Y[(size_t)row * 64 + lane] * scale + shift, 0.f) * w;
        #pragma unroll
        for (int o = 32; o > 0; o >>= 1) v += __shfl_down(v, o, 64);
        if (lane == 0) hs3[row] = v * dinv[row];
    }
}

// ---- layer-3 aggregation: wave per node, lane-parallel edge gather ----
__global__ void agg1(const float* __restrict__ hs3, const int* __restrict__ csr,
                     const int* __restrict__ off, const float* __restrict__ dinv,
                     const float* __restrict__ b3, float* __restrict__ out, int n) {
    float b = b3[0];
    int lane  = threadIdx.x & 63;
    int wave  = (blockIdx.x * blockDim.x + threadIdx.x) >> 6;
    int nwave = (gridDim.x * blockDim.x) >> 6;
    for (int i = wave; i < n; i += nwave) {
        int beg = off[i], end = off[i + 1];
        float acc = 0.f;
        for (int e = beg + lane; e < end; e += 64) acc += hs3[csr[e]];
        #pragma unroll
        for (int o = 32; o > 0; o >>= 1) acc += __shfl_down(acc, o, 64);
        if (lane == 0) out[i] = dinv[i] * (acc + hs3[i]) + b;
    }
}

extern "C" void kernel_launch(void* const* d_in, const int* in_sizes, int n_in,
                              void* d_out, int out_size, void* d_ws, size_t ws_size,
                              hipStream_t stream) {
    const float* x   = (const float*)d_in[0];
    const float* W1  = (const float*)d_in[1];
    const float* b1  = (const float*)d_in[2];
    const float* g1  = (const float*)d_in[3];
    const float* bt1 = (const float*)d_in[4];
    const float* W2  = (const float*)d_in[5];
    const float* b2  = (const float*)d_in[6];
    const float* g2  = (const float*)d_in[7];
    const float* bt2 = (const float*)d_in[8];
    const float* W3  = (const float*)d_in[9];
    const float* b3  = (const float*)d_in[10];
    const int*  edge = (const int*)d_in[11];

    int n = in_sizes[0] / 64;
    int E = in_sizes[11] / 2;
    const int* src = edge;
    const int* dst = edge + E;
    float* out = (float*)d_out;
    int nblk = (n + 255) / 256;

    // ---- workspace ----
    char* p = (char*)d_ws;
    double* stats = (double*)p;            p += 256 * sizeof(double);  // L1:0..127, L2:128..255
    float* dinv   = (float*)p;             p += ((n + 63) & ~63) * sizeof(float);
    int* degi     = (int*)p;               p += ((n + 63) & ~63) * sizeof(int);
    int* off      = (int*)p;               p += ((n + 64) & ~63) * sizeof(int);
    int* cur      = (int*)p;               p += ((n + 63) & ~63) * sizeof(int);
    int* part     = (int*)p;               p += 256 * sizeof(int);
    int* csr      = (int*)p;               p += (size_t)E * sizeof(int);
    unsigned* A   = (unsigned*)p;          p += (size_t)n * 32 * sizeof(unsigned); // bf16 T (128B/row)
    float* B      = (float*)p;             p += (size_t)n * 64 * sizeof(float);    // Y1/Y2 (f32)
    float* hs3    = (float*)p;             /* n floats */

    hipMemsetAsync(degi, 0, n * sizeof(int), stream);
    hipMemsetAsync(stats, 0, 256 * sizeof(double), stream);

    // CSR build
    deg_count<<<2048, 256, 0, stream>>>(dst, degi, E);
    scan_part<<<nblk, 256, 0, stream>>>(degi, part, n);
    scan_root<<<1, 256, 0, stream>>>(part, nblk);
    scan_write<<<nblk, 256, 0, stream>>>(degi, part, off, cur, dinv, n);
    csr_fill_x<<<2048, 256, 0, stream>>>(src, dst, cur, csr, E, n);

    // layer 1: T1 = bf16(x*dinv) ; y1 = dinv*(gather-sum T1)@W1 + b1
    prescale<<<1024, 256, 0, stream>>>(x, dinv, A, n);
    agg_mm<<<2048, 256, 0, stream>>>((const uint4*)A, csr, off, dinv, W1, b1,
                                     stats, B, n);
    // layer 2: T2 = bf16(relu(BN1(y1))*dinv) ; y2 = dinv*(gather-sum T2)@W2 + b2
    bnrelu_scale<<<1024, 256, 0, stream>>>(B, stats, g1, bt1, dinv, A, n);
    agg_mm<<<2048, 256, 0, stream>>>((const uint4*)A, csr, off, dinv, W2, b2,
                                     stats + 128, B, n);
    // layer 3 (f32 path, tiny)
    head_w3<<<2048, 256, 0, stream>>>(B, stats + 128, g2, bt2, W3, dinv, hs3, n);
    agg1<<<2048, 256, 0, stream>>>(hs3, csr, off, dinv, b3, out, n);
}